// Round 2
// baseline (2279.908 us; speedup 1.0000x reference)
//
#include <hip/hip_runtime.h>

typedef unsigned short u16;
typedef unsigned int   u32;
using short8  = __attribute__((ext_vector_type(8))) short;
using short4v = __attribute__((ext_vector_type(4))) short;
using f32x4   = __attribute__((ext_vector_type(4))) float;
using f32x2   = __attribute__((ext_vector_type(2))) float;

#define N_USER 200000
#define N_NEWS 100000
#define N_SRCT 5000
#define N_FOLW 200000
#define E_POSTS 500000
#define E_PUB   100000
#define E_FOLL  1000000
#define NCNT    805000            // total count entries across 6 relations
#define NPOOL   3200000           // total CSR pool entries (sum of E per relation)

__device__ __forceinline__ float bf2f(u16 h) {
  union { u32 u; float f; } v; v.u = ((u32)h) << 16; return v.f;
}
__device__ __forceinline__ u16 f2bf(float f) {
  union { float f; u32 u; } v; v.f = f;
  u32 r = v.u + 0x7FFFu + ((v.u >> 16) & 1u);
  return (u16)(r >> 16);
}

// ---------------- degree counting (into int array) ----------------
__global__ void count_k(const int* __restrict__ idx, int n, int* __restrict__ cnt) {
  int i = blockIdx.x * 256 + threadIdx.x;
  if (i < n) atomicAdd(&cnt[idx[i]], 1);
}
__global__ void rsqrt_k(const int* __restrict__ cnti, float* __restrict__ out, int n) {
  int i = blockIdx.x * 256 + threadIdx.x;
  if (i < n) {
    int c = cnti[i];
    out[i] = rsqrtf((float)(c > 0 ? c : 1));
  }
}

// ---------------- exclusive prefix scan over NCNT ints (3 kernels) ----------------
__global__ void scan1_k(const int* __restrict__ in, int* __restrict__ out,
                        int* __restrict__ bsum, int n) {
  __shared__ int s[256];
  int tid = threadIdx.x;
  int gid = blockIdx.x * 256 + tid;
  int v = (gid < n) ? in[gid] : 0;
  s[tid] = v;
  __syncthreads();
  for (int d = 1; d < 256; d <<= 1) {
    int t = (tid >= d) ? s[tid - d] : 0;
    __syncthreads();
    s[tid] += t;
    __syncthreads();
  }
  if (gid < n) out[gid] = s[tid];
  if (tid == 255) bsum[blockIdx.x] = s[255];
}
__global__ void scan2_k(int* __restrict__ bsum, int m) {
  __shared__ int p[256];
  __shared__ int buf[3328];
  int tid = threadIdx.x;
  int chunk = (m + 255) / 256;
  int run = 0;
  for (int i = 0; i < chunk; ++i) {
    int idx = tid * chunk + i;
    int v = (idx < m) ? bsum[idx] : 0;
    if (idx < m) buf[idx] = run;   // exclusive within chunk
    run += v;
  }
  p[tid] = run;
  __syncthreads();
  int own = run;
  for (int d = 1; d < 256; d <<= 1) {
    int t = (tid >= d) ? p[tid - d] : 0;
    __syncthreads();
    p[tid] += t;
    __syncthreads();
  }
  int base = p[tid] - own;         // exclusive across chunks
  for (int i = 0; i < chunk; ++i) {
    int idx = tid * chunk + i;
    if (idx < m) bsum[idx] = buf[idx] + base;
  }
}
__global__ void scan3_k(int* __restrict__ offs, const int* __restrict__ cnti,
                        const int* __restrict__ bsum, int n) {
  int gid = blockIdx.x * 256 + threadIdx.x;
  if (gid < n) offs[gid] = offs[gid] - cnti[gid] + bsum[blockIdx.x];
}

// ---------------- CSR fill: pool[offs[d]+cursor++] = src[e] ----------------
__global__ void csr_fill_k(const int* __restrict__ src, const int* __restrict__ dst,
                           const int* __restrict__ offs, int* __restrict__ curs,
                           int* __restrict__ pool, int E, int cntOff) {
  int e = blockIdx.x * 256 + threadIdx.x;
  if (e >= E) return;
  int d = dst[e] + cntOff;
  int p = offs[d] + atomicAdd(&curs[d], 1);
  pool[p] = src[e];
}

// ---------------- fp32 -> bf16 convert + K-pad, 8 elems/thread ----------------
__global__ void cvt_pad8_k(const float* __restrict__ X, u16* __restrict__ P,
                           int Ksrc, int Kdst, int total8) {
  int i = blockIdx.x * 256 + threadIdx.x;
  if (i >= total8) return;
  int base = i * 8;                  // Kdst % 8 == 0 -> group stays in one row
  short8 o;
  if (Ksrc == Kdst) {
    f32x4 a = *(const f32x4*)(X + base);
    f32x4 b = *(const f32x4*)(X + base + 4);
#pragma unroll
    for (int j = 0; j < 4; ++j) { o[j] = (short)f2bf(a[j]); o[j + 4] = (short)f2bf(b[j]); }
  } else {
    int row = base / Kdst;
    int k = base - row * Kdst;
#pragma unroll
    for (int j = 0; j < 8; ++j) {
      int kk = k + j;
      o[j] = (kk < Ksrc) ? (short)f2bf(X[(size_t)row * Ksrc + kk]) : (short)0;
    }
  }
  *(short8*)(P + base) = o;
}

// ---- weight: fp32 [nmat][Ksrc][128] -> bf16 k-major [nmat][128][Kdst] (K-padded) ----
__global__ void trans_w_k(const float* __restrict__ W, u16* __restrict__ WT,
                          int Ksrc, int Kdst, int total) {
  int i = blockIdx.x * 256 + threadIdx.x;
  if (i >= total) return;
  int per = Kdst << 7;
  int m = i / per, rem = i - m * per;
  int n = rem / Kdst, k = rem - n * Kdst;
  WT[i] = (k < Ksrc) ? f2bf(W[(size_t)m * Ksrc * 128 + (size_t)k * 128 + n]) : (u16)0;
}

// ---------------- MFMA GEMM: C[M,128] = act((A[M,K] @ W) * rowscale + bias) ----------------
__global__ __launch_bounds__(256, 2) void gemm_bf16(
    const u16* __restrict__ A, int lda, int M, int K,
    const u16* __restrict__ WT,
    const float* __restrict__ bias,     // 128 fp32 or null
    const float* __restrict__ rowscale, // M fp32 or null
    u16* __restrict__ C, int leaky)
{
  __shared__ u16 Ws[128][136];   // [n][k-chunk], +8 pad
  const int tid  = threadIdx.x;
  const int wave = tid >> 6;
  const int lane = tid & 63;
  const int l15  = lane & 15;
  const int l4   = lane >> 4;
  const int rowBase = blockIdx.x * 128 + wave * 32;

  f32x4 acc[2][8];
#pragma unroll
  for (int g = 0; g < 2; ++g)
#pragma unroll
    for (int c = 0; c < 8; ++c) acc[g][c] = (f32x4){0.f, 0.f, 0.f, 0.f};

  const int r0 = (rowBase + l15 < M) ? rowBase + l15 : M - 1;
  const int r1 = (rowBase + 16 + l15 < M) ? rowBase + 16 + l15 : M - 1;

  for (int kb = 0; kb < K; kb += 128) {
    const int chunkK = (K - kb < 128) ? (K - kb) : 128;
    __syncthreads();
    for (int fl = tid * 8; fl < (chunkK << 7); fl += 2048) {
      int n = fl / chunkK;
      int kk = fl - n * chunkK;
      *(short8*)(&Ws[n][kk]) = *(const short8*)(WT + (size_t)n * K + kb + kk);
    }
    __syncthreads();
    const int nsteps = chunkK >> 5;
    for (int ks = 0; ks < nsteps; ++ks) {
      const int kg = ks * 32 + l4 * 8;
      short8 a0 = *(const short8*)(A + (size_t)r0 * lda + kb + kg);
      short8 a1 = *(const short8*)(A + (size_t)r1 * lda + kb + kg);
#pragma unroll
      for (int c = 0; c < 8; ++c) {
        short8 b = *(const short8*)(&Ws[c * 16 + l15][kg]);
        acc[0][c] = __builtin_amdgcn_mfma_f32_16x16x32_bf16(a0, b, acc[0][c], 0, 0, 0);
        acc[1][c] = __builtin_amdgcn_mfma_f32_16x16x32_bf16(a1, b, acc[1][c], 0, 0, 0);
      }
    }
  }

  float bvals[8];
#pragma unroll
  for (int c = 0; c < 8; ++c) bvals[c] = bias ? bias[c * 16 + l15] : 0.f;

#pragma unroll
  for (int g = 0; g < 2; ++g) {
#pragma unroll
    for (int r = 0; r < 4; ++r) {
      int row = rowBase + g * 16 + l4 * 4 + r;
      if (row >= M) continue;
      float sc = rowscale ? rowscale[row] : 1.f;
#pragma unroll
      for (int c = 0; c < 8; ++c) {
        float v = acc[g][c][r] * sc + bvals[c];
        if (leaky) v = (v > 0.f) ? v : 0.01f * v;
        C[(size_t)row * 128 + c * 16 + l15] = f2bf(v);
      }
    }
  }
}

// ------- fused gather-aggregate + mean + bias + lrelu -------
// One wave per destination row. Wave = 4 edge-slots x 16 lanes.
// Lane l: edge e+(l>>4), columns (l&15)*8..+7 via one short8 (16B) load.
// Butterfly (xor 16,32) merges edge-slots; lanes 0-15 write.
__global__ __launch_bounds__(256) void gather_conv(
    const u16* __restrict__ T, const int* __restrict__ pool,
    const int* __restrict__ offs, const int* __restrict__ cnti,
    const float* __restrict__ rsin,
    int co0, int to0, int co1, int to1,
    const float* __restrict__ b1, const float* __restrict__ b2, float invn,
    u16* __restrict__ out_bf, float* __restrict__ out_f, int nDst)
{
  const int wave = threadIdx.x >> 6;
  const int lane = threadIdx.x & 63;
  const int sub  = lane >> 4;        // edge slot 0..3
  const int l15  = lane & 15;        // column group
  const int d = blockIdx.x * 4 + wave;
  if (d >= nDst) return;

  float s[8];
#pragma unroll
  for (int j = 0; j < 8; ++j) s[j] = 0.f;

  int co = co0, to = to0;
#pragma unroll 1
  for (int r = 0; r < 2; ++r) {
    if (co < 0) break;
    const int off = offs[co + d];
    const int cnt = cnti[co + d];
    const float sc = rsin[co + d];
    float p[8];
#pragma unroll
    for (int j = 0; j < 8; ++j) p[j] = 0.f;
#pragma unroll 1
    for (int e = 0; e < cnt; e += 4) {
      int ee = e + sub;
      bool valid = ee < cnt;
      int idx = pool[off + (valid ? ee : cnt - 1)];
      short8 w = *(const short8*)(T + (((size_t)(to + idx)) << 7) + l15 * 8);
      if (valid) {
#pragma unroll
        for (int j = 0; j < 8; ++j) p[j] += bf2f((u16)w[j]);
      }
    }
#pragma unroll
    for (int j = 0; j < 8; ++j) s[j] += p[j] * sc;
    co = co1; to = to1;
  }

  // merge the 4 edge-slots
#pragma unroll
  for (int j = 0; j < 8; ++j) {
    s[j] += __shfl_xor(s[j], 16, 64);
    s[j] += __shfl_xor(s[j], 32, 64);
  }

  if (sub == 0) {
    const int col = l15 * 8;
    float v[8];
#pragma unroll
    for (int j = 0; j < 8; ++j) {
      float bb = b1[col + j] + (b2 ? b2[col + j] : 0.f);
      float x = (s[j] + bb) * invn;
      v[j] = (x > 0.f) ? x : 0.01f * x;
    }
    if (out_f) {
      float* op = out_f + (((size_t)d) << 7) + col;
      *(f32x4*)op       = (f32x4){v[0], v[1], v[2], v[3]};
      *(f32x4*)(op + 4) = (f32x4){v[4], v[5], v[6], v[7]};
    } else {
      short8 o;
#pragma unroll
      for (int j = 0; j < 8; ++j) o[j] = (short)f2bf(v[j]);
      *(short8*)(out_bf + (((size_t)d) << 7) + col) = o;
    }
  }
}

// ---------------- final linear: [rows,128] @ [128,2] + b (all fp32) ----------------
__global__ __launch_bounds__(256) void linear_k(
    const float* __restrict__ H, const float* __restrict__ Wl,
    const float* __restrict__ bl, float* __restrict__ OUT, int rows)
{
  __shared__ float w0[128], w1[128];
  int tid = threadIdx.x;
  if (tid < 128) { w0[tid] = Wl[tid * 2]; w1[tid] = Wl[tid * 2 + 1]; }
  __syncthreads();
  int row = blockIdx.x * 256 + tid;
  if (row >= rows) return;
  const float* hp = H + ((size_t)row << 7);
  float s0 = 0.f, s1 = 0.f;
#pragma unroll
  for (int k = 0; k < 128; k += 4) {
    f32x4 h4 = *(const f32x4*)(hp + k);
#pragma unroll
    for (int j = 0; j < 4; ++j) {
      s0 += h4[j] * w0[k + j];
      s1 += h4[j] * w1[k + j];
    }
  }
  OUT[(size_t)row * 2]     = s0 + bl[0];
  OUT[(size_t)row * 2 + 1] = s1 + bl[1];
}

extern "C" void kernel_launch(void* const* d_in, const int* in_sizes, int n_in,
                              void* d_out, int out_size, void* d_ws, size_t ws_size,
                              hipStream_t stream)
{
  (void)in_sizes; (void)n_in; (void)out_size; (void)ws_size;

  // ---- workspace carve-up ----
  char* wp = (char*)d_ws;
  auto take = [&](size_t bytes) { void* p = wp; wp += (bytes + 255) & ~(size_t)255; return p; };
  u16*   ARENA = (u16*)take(206080000);  // first: XB bf16 inputs (167.7MB); later: T pool (206.1MB)
  u16*   HA  = (u16*)take(129280000);    // 505000*128 bf16
  u16*   HB  = (u16*)take(129280000);
  u16*   WTA = (u16*)take(1884160);      // transposed bf16 weights arena
  float* CNT = (float*)take(3220000);    // 805000 f32 rsqrt values
  int*   CNTI = (int*)take(3220000);     // 805000 int degree counts
  int*   OFFS = (int*)take(3220000);     // 805000 int CSR offsets (global exclusive scan)
  int*   CURS = (int*)take(3220000);     // 805000 int fill cursors
  int*   POOL = (int*)take(12800000);    // 3.2M int CSR src indices
  int*   BSUM = (int*)take(16384);       // scan block sums (3145)
  u16*   XB  = ARENA;                    // bf16 input arena — dead before T-pool use
  u16*   TP  = ARENA;                    // per-relation GEMM-output pool

  const int rowOff[4] = {0, 200000, 300000, 305000};   // user,news,source,follower
  const int Nt[4]     = {N_USER, N_NEWS, N_SRCT, N_FOLW};
  const size_t XOFF[4] = {0, 25600000, 57600000, 58240000};
  const int KD[4] = {128, 320, 128, 128};              // padded K per type
  const int KS[4] = {128, 300, 128, 128};
  const int WT1[4] = {0, 16384, 57344, 73728};
  const int WT2 = 90112, WTC1 = 155648, WTC2 = 548864;

  // relation table: E, src idx, dst idx, src type, dst type, srcCnt off, dstCnt off, T-row off
  struct RelG { int E, srcIdx, dstIdx, srcType, dstType, srcCnt, dstCnt, tOff; };
  const RelG rels[6] = {
    {E_POSTS, 26, 27, 0, 1, 0,      200000, 0},       // posts: user->news
    {E_POSTS, 27, 26, 1, 0, 200000, 0,      200000},  // posted_by: news->user
    {E_PUB,   28, 29, 2, 1, 300000, 305000, 300000},  // publishes: source->news
    {E_PUB,   29, 28, 1, 2, 305000, 300000, 305000},  // published_by: news->source
    {E_FOLL,  30, 31, 3, 0, 405000, 605000, 405000},  // follows: follower->user
    {E_FOLL,  31, 30, 0, 3, 605000, 405000, 605000},  // followed_by: user->follower
  };

  // ---- degrees (int) ----
  hipMemsetAsync(CNTI, 0, NCNT * 4, stream);
  count_k<<<(E_POSTS + 255) / 256, 256, 0, stream>>>((const int*)d_in[26], E_POSTS, CNTI + 0);
  count_k<<<(E_POSTS + 255) / 256, 256, 0, stream>>>((const int*)d_in[27], E_POSTS, CNTI + 200000);
  count_k<<<(E_PUB   + 255) / 256, 256, 0, stream>>>((const int*)d_in[28], E_PUB,   CNTI + 300000);
  count_k<<<(E_PUB   + 255) / 256, 256, 0, stream>>>((const int*)d_in[29], E_PUB,   CNTI + 305000);
  count_k<<<(E_FOLL  + 255) / 256, 256, 0, stream>>>((const int*)d_in[30], E_FOLL,  CNTI + 405000);
  count_k<<<(E_FOLL  + 255) / 256, 256, 0, stream>>>((const int*)d_in[31], E_FOLL,  CNTI + 605000);
  rsqrt_k<<<(NCNT + 255) / 256, 256, 0, stream>>>(CNTI, CNT, NCNT);

  // ---- CSR build (once; graph static across layers) ----
  const int scanBlocks = (NCNT + 255) / 256;   // 3145
  scan1_k<<<scanBlocks, 256, 0, stream>>>(CNTI, OFFS, BSUM, NCNT);
  scan2_k<<<1, 256, 0, stream>>>(BSUM, scanBlocks);
  scan3_k<<<scanBlocks, 256, 0, stream>>>(OFFS, CNTI, BSUM, NCNT);
  hipMemsetAsync(CURS, 0, NCNT * 4, stream);
  for (int r = 0; r < 6; ++r) {
    csr_fill_k<<<(rels[r].E + 255) / 256, 256, 0, stream>>>(
        (const int*)d_in[rels[r].srcIdx], (const int*)d_in[rels[r].dstIdx],
        OFFS, CURS, POOL, rels[r].E, rels[r].dstCnt);
  }

  // ---- convert inputs fp32->bf16 (+pad news K 300->320) into XB ----
  for (int t = 0; t < 4; ++t) {
    int total8 = (Nt[t] * KD[t]) / 8;
    cvt_pad8_k<<<(total8 + 255) / 256, 256, 0, stream>>>(
        (const float*)d_in[t], XB + XOFF[t], KS[t], KD[t], total8);
  }
  // ---- weights fp32 -> bf16 k-major (+pad news Wi1) ----
  auto transL = [&](int idx, int wtOff, int Ksrc, int Kdst, int total) {
    trans_w_k<<<(total + 255) / 256, 256, 0, stream>>>(
        (const float*)d_in[idx], WTA + wtOff, Ksrc, Kdst, total);
  };
  transL(4,  WT1[0], 128, 128, 16384);
  transL(6,  WT1[1], 300, 320, 40960);
  transL(8,  WT1[2], 128, 128, 16384);
  transL(10, WT1[3], 128, 128, 16384);
  transL(12, WT2,    128, 128, 65536);    // Wi2 (4 mats)
  transL(14, WTC1,   128, 128, 393216);   // conv1_W (24 mats)
  transL(16, WTC2,   128, 128, 393216);   // conv2_W (24 mats)

  auto gemmL = [&](const u16* A, int lda, int M, int K, const u16* WTp,
                   const float* bias, const float* rs, u16* C, int leaky) {
    gemm_bf16<<<(M + 127) / 128, 256, 0, stream>>>(A, lda, M, K, WTp, bias, rs, C, leaky);
  };

  // ---- stage1: h = lrelu(x @ Wi1 + bi1) -> HA ----
  for (int t = 0; t < 4; ++t)
    gemmL(XB + XOFF[t], KD[t], Nt[t], KD[t], WTA + WT1[t],
          (const float*)d_in[5 + 2 * t], nullptr, HA + (size_t)rowOff[t] * 128, 1);

  // ---- stage2: h = lrelu(h @ Wi2 + bi2) -> HB ----
  for (int t = 0; t < 4; ++t)
    gemmL(HA + (size_t)rowOff[t] * 128, 128, Nt[t], 128, WTA + WT2 + t * 16384,
          (const float*)d_in[13] + t * 128, nullptr, HB + (size_t)rowOff[t] * 128, 1);

  const size_t H1OFF[4] = {1010000, 26610000, 39410000, 40050000};
  const size_t LOFF[4]  = {0, 400000, 600000, 610000};
  const int relsOf[4][2] = {{1, 4}, {0, 2}, {3, -1}, {5, -1}};
  float* OUT = (float*)d_out;

  // ---- conv layers (XB dead from here; T pool takes over ARENA) ----
  for (int layer = 0; layer < 2; ++layer) {
    const u16* HIn     = layer ? HA : HB;
    const u16* wt      = WTA + (layer ? WTC2 : WTC1);
    const float* convb = (const float*)d_in[layer ? 17 : 15];
    // T_r = (h_src * rsqrt(deg_out)) @ W[dstType][r]  (row-scale commutes with @W)
    for (int r = 0; r < 6; ++r) {
      const RelG& q = rels[r];
      gemmL(HIn + (size_t)rowOff[q.srcType] * 128, 128, Nt[q.srcType], 128,
            wt + (size_t)(q.dstType * 6 + r) * 16384, nullptr, CNT + q.srcCnt,
            TP + (size_t)q.tOff * 128, 0);
    }
    // fused gather + mean + bias + lrelu per dst type
    for (int k = 0; k < 4; ++k) {
      int r1 = relsOf[k][0], r2 = relsOf[k][1];
      int co0 = rels[r1].dstCnt, to0 = rels[r1].tOff;
      int co1 = (r2 >= 0) ? rels[r2].dstCnt : -1;
      int to1 = (r2 >= 0) ? rels[r2].tOff : 0;
      const float* b1 = convb + (size_t)(k * 6 + r1) * 128;
      const float* b2 = (r2 >= 0) ? convb + (size_t)(k * 6 + r2) * 128 : nullptr;
      float invn = (r2 >= 0) ? 0.5f : 1.0f;
      u16* obf  = layer ? nullptr : (HA + (size_t)rowOff[k] * 128);
      float* of = layer ? (OUT + H1OFF[k]) : nullptr;
      gather_conv<<<(Nt[k] + 3) / 4, 256, 0, stream>>>(
          TP, POOL, OFFS, CNTI, CNT, co0, to0, co1, to1, b1, b2, invn, obf, of, Nt[k]);
    }
  }

  // ---- final linear: logits = h1 @ Wl + bl ----
  for (int k = 0; k < 4; ++k)
    linear_k<<<(Nt[k] + 255) / 256, 256, 0, stream>>>(
        OUT + H1OFF[k], (const float*)d_in[18 + 2 * k], (const float*)d_in[19 + 2 * k],
        OUT + LOFF[k], Nt[k]);
}

// Round 3
// 2024.015 us; speedup vs baseline: 1.1264x; 1.1264x over previous
//
#include <hip/hip_runtime.h>

typedef unsigned short u16;
typedef unsigned int   u32;
using short8  = __attribute__((ext_vector_type(8))) short;
using short4v = __attribute__((ext_vector_type(4))) short;
using f32x4   = __attribute__((ext_vector_type(4))) float;
using f32x2   = __attribute__((ext_vector_type(2))) float;

#define N_USER 200000
#define N_NEWS 100000
#define N_SRCT 5000
#define N_FOLW 200000
#define E_POSTS 500000
#define E_PUB   100000
#define E_FOLL  1000000
#define NCNT    805000            // total count entries across 6 relations
#define NPOOL   3200000           // total CSR pool entries

__device__ __forceinline__ float bf2f(u16 h) {
  union { u32 u; float f; } v; v.u = ((u32)h) << 16; return v.f;
}
__device__ __forceinline__ u16 f2bf(float f) {
  union { float f; u32 u; } v; v.f = f;
  u32 r = v.u + 0x7FFFu + ((v.u >> 16) & 1u);
  return (u16)(r >> 16);
}

// ---------------- merged degree counting over all 6 relations ----------------
__global__ void count6_k(const int* __restrict__ p0, const int* __restrict__ p1,
                         const int* __restrict__ p2, const int* __restrict__ p3,
                         const int* __restrict__ p4, const int* __restrict__ p5,
                         int* __restrict__ cnt) {
  int i = blockIdx.x * 256 + threadIdx.x;   // 3.2M total, grid exact
  const int* p; int off;
  if      (i < 500000)  { p = p0; off = 0; }
  else if (i < 1000000) { p = p1; i -= 500000;  off = 200000; }
  else if (i < 1100000) { p = p2; i -= 1000000; off = 300000; }
  else if (i < 1200000) { p = p3; i -= 1100000; off = 305000; }
  else if (i < 2200000) { p = p4; i -= 1200000; off = 405000; }
  else                  { p = p5; i -= 2200000; off = 605000; }
  atomicAdd(&cnt[off + p[i]], 1);
}
__global__ void rsqrt_k(const int* __restrict__ cnti, float* __restrict__ out, int n) {
  int i = blockIdx.x * 256 + threadIdx.x;
  if (i < n) {
    int c = cnti[i];
    out[i] = rsqrtf((float)(c > 0 ? c : 1));
  }
}

// ---------------- exclusive prefix scan over NCNT ints (3 kernels) ----------------
__global__ void scan1_k(const int* __restrict__ in, int* __restrict__ out,
                        int* __restrict__ bsum, int n) {
  __shared__ int s[256];
  int tid = threadIdx.x;
  int gid = blockIdx.x * 256 + tid;
  int v = (gid < n) ? in[gid] : 0;
  s[tid] = v;
  __syncthreads();
  for (int d = 1; d < 256; d <<= 1) {
    int t = (tid >= d) ? s[tid - d] : 0;
    __syncthreads();
    s[tid] += t;
    __syncthreads();
  }
  if (gid < n) out[gid] = s[tid];
  if (tid == 255) bsum[blockIdx.x] = s[255];
}
__global__ void scan2_k(int* __restrict__ bsum, int m) {
  __shared__ int p[256];
  __shared__ int buf[3328];
  int tid = threadIdx.x;
  int chunk = (m + 255) / 256;
  int run = 0;
  for (int i = 0; i < chunk; ++i) {
    int idx = tid * chunk + i;
    int v = (idx < m) ? bsum[idx] : 0;
    if (idx < m) buf[idx] = run;
    run += v;
  }
  p[tid] = run;
  __syncthreads();
  int own = run;
  for (int d = 1; d < 256; d <<= 1) {
    int t = (tid >= d) ? p[tid - d] : 0;
    __syncthreads();
    p[tid] += t;
    __syncthreads();
  }
  int base = p[tid] - own;
  for (int i = 0; i < chunk; ++i) {
    int idx = tid * chunk + i;
    if (idx < m) bsum[idx] = buf[idx] + base;
  }
}
__global__ void scan3_k(int* __restrict__ offs, const int* __restrict__ cnti,
                        const int* __restrict__ bsum, int n) {
  int gid = blockIdx.x * 256 + threadIdx.x;
  if (gid < n) offs[gid] = offs[gid] - cnti[gid] + bsum[blockIdx.x];
}

// ---------------- merged CSR fill over all 6 relations ----------------
__global__ void fill6_k(const int* __restrict__ s0, const int* __restrict__ d0,
                        const int* __restrict__ s1, const int* __restrict__ d1,
                        const int* __restrict__ s2, const int* __restrict__ d2,
                        const int* __restrict__ s3, const int* __restrict__ d3,
                        const int* __restrict__ s4, const int* __restrict__ d4,
                        const int* __restrict__ s5, const int* __restrict__ d5,
                        const int* __restrict__ offs, int* __restrict__ curs,
                        int* __restrict__ pool) {
  int i = blockIdx.x * 256 + threadIdx.x;   // 3.2M total
  const int* sp; const int* dp; int off;
  if      (i < 500000)  { sp = s0; dp = d0; off = 200000; }
  else if (i < 1000000) { sp = s1; dp = d1; i -= 500000;  off = 0; }
  else if (i < 1100000) { sp = s2; dp = d2; i -= 1000000; off = 305000; }
  else if (i < 1200000) { sp = s3; dp = d3; i -= 1100000; off = 300000; }
  else if (i < 2200000) { sp = s4; dp = d4; i -= 1200000; off = 605000; }
  else                  { sp = s5; dp = d5; i -= 2200000; off = 405000; }
  int dd = dp[i] + off;
  int p = offs[dd] + atomicAdd(&curs[dd], 1);
  pool[p] = sp[i];
}

// ---- 55 uniform 128x128 weight transposes in one kernel ----
__global__ void trans55_k(const float* __restrict__ w0, const float* __restrict__ w1,
                          const float* __restrict__ w2, const float* __restrict__ w3,
                          const float* __restrict__ w4, const float* __restrict__ w5,
                          u16* __restrict__ WT) {
  int i = blockIdx.x * 256 + threadIdx.x;   // 55*16384 = 901120, grid 3520 exact
  int m = i >> 14, rem = i & 16383;
  int n = rem >> 7, k = rem & 127;
  const float* W; int lm, dstOff;
  if      (m < 1)  { W = w0; lm = m;      dstOff = 0; }
  else if (m < 2)  { W = w1; lm = m - 1;  dstOff = 57344; }
  else if (m < 3)  { W = w2; lm = m - 2;  dstOff = 73728; }
  else if (m < 7)  { W = w3; lm = m - 3;  dstOff = 90112; }
  else if (m < 31) { W = w4; lm = m - 7;  dstOff = 155648; }
  else             { W = w5; lm = m - 31; dstOff = 548864; }
  WT[dstOff + (lm << 14) + (n << 7) + k] = f2bf(W[(size_t)(lm << 14) + (k << 7) + n]);
}
// news Wi1: fp32 [300][128] -> bf16 k-major [128][320]
__global__ void trans_w_k(const float* __restrict__ W, u16* __restrict__ WT,
                          int Ksrc, int Kdst, int total) {
  int i = blockIdx.x * 256 + threadIdx.x;
  if (i >= total) return;
  int n = i / Kdst, k = i - n * Kdst;
  WT[i] = (k < Ksrc) ? f2bf(W[(size_t)k * 128 + n]) : (u16)0;
}

// ---------------- MFMA GEMM: C[M,128] = act((A[M,K] @ W) * rowscale + bias) ----------------
// A either bf16 [M,lda] or fp32 [M,lda] (A32 path, valid cols = Ks, rest zero-padded).
__device__ __forceinline__ short8 ldA32(const float* __restrict__ rowp, int Ks, int k0) {
  short8 a;
  if (k0 + 8 <= Ks) {
    f32x4 u = *(const f32x4*)(rowp + k0);
    f32x4 v = *(const f32x4*)(rowp + k0 + 4);
#pragma unroll
    for (int j = 0; j < 4; ++j) { a[j] = (short)f2bf(u[j]); a[j + 4] = (short)f2bf(v[j]); }
  } else {
#pragma unroll
    for (int j = 0; j < 8; ++j) {
      int kk = k0 + j;
      a[j] = (kk < Ks) ? (short)f2bf(rowp[kk]) : (short)0;
    }
  }
  return a;
}

__global__ __launch_bounds__(256, 2) void gemm_bf16(
    const u16* __restrict__ A, const float* __restrict__ A32, int Ks,
    int lda, int M, int K,
    const u16* __restrict__ WT,
    const float* __restrict__ bias,     // 128 fp32 or null
    const float* __restrict__ rowscale, // M fp32 or null
    u16* __restrict__ C, int leaky)
{
  __shared__ u16 Ws[128][136];   // [n][k-chunk], +8 pad
  const int tid  = threadIdx.x;
  const int wave = tid >> 6;
  const int lane = tid & 63;
  const int l15  = lane & 15;
  const int l4   = lane >> 4;
  const int rowBase = blockIdx.x * 128 + wave * 32;

  f32x4 acc[2][8];
#pragma unroll
  for (int g = 0; g < 2; ++g)
#pragma unroll
    for (int c = 0; c < 8; ++c) acc[g][c] = (f32x4){0.f, 0.f, 0.f, 0.f};

  const int r0 = (rowBase + l15 < M) ? rowBase + l15 : M - 1;
  const int r1 = (rowBase + 16 + l15 < M) ? rowBase + 16 + l15 : M - 1;

  for (int kb = 0; kb < K; kb += 128) {
    const int chunkK = (K - kb < 128) ? (K - kb) : 128;
    __syncthreads();
    for (int fl = tid * 8; fl < (chunkK << 7); fl += 2048) {
      int n = fl / chunkK;
      int kk = fl - n * chunkK;
      *(short8*)(&Ws[n][kk]) = *(const short8*)(WT + (size_t)n * K + kb + kk);
    }
    __syncthreads();
    const int nsteps = chunkK >> 5;
    for (int ks = 0; ks < nsteps; ++ks) {
      const int kg = ks * 32 + l4 * 8;
      short8 a0, a1;
      if (A32) {
        a0 = ldA32(A32 + (size_t)r0 * lda, Ks, kb + kg);
        a1 = ldA32(A32 + (size_t)r1 * lda, Ks, kb + kg);
      } else {
        a0 = *(const short8*)(A + (size_t)r0 * lda + kb + kg);
        a1 = *(const short8*)(A + (size_t)r1 * lda + kb + kg);
      }
#pragma unroll
      for (int c = 0; c < 8; ++c) {
        short8 b = *(const short8*)(&Ws[c * 16 + l15][kg]);
        acc[0][c] = __builtin_amdgcn_mfma_f32_16x16x32_bf16(a0, b, acc[0][c], 0, 0, 0);
        acc[1][c] = __builtin_amdgcn_mfma_f32_16x16x32_bf16(a1, b, acc[1][c], 0, 0, 0);
      }
    }
  }

  float bvals[8];
#pragma unroll
  for (int c = 0; c < 8; ++c) bvals[c] = bias ? bias[c * 16 + l15] : 0.f;

#pragma unroll
  for (int g = 0; g < 2; ++g) {
#pragma unroll
    for (int r = 0; r < 4; ++r) {
      int row = rowBase + g * 16 + l4 * 4 + r;
      if (row >= M) continue;
      float sc = rowscale ? rowscale[row] : 1.f;
#pragma unroll
      for (int c = 0; c < 8; ++c) {
        float v = acc[g][c][r] * sc + bvals[c];
        if (leaky) v = (v > 0.f) ? v : 0.01f * v;
        C[(size_t)row * 128 + c * 16 + l15] = f2bf(v);
      }
    }
  }
}

// ------- fused gather-aggregate + mean + bias + lrelu -------
// One wave per destination row. Both relations fused into one virtual edge
// list (tot = cnt0+cnt1). 4 edge-slots x 16 lanes, unroll-2 (8 edges in
// flight). Loads are PREDICATED: invalid slots issue nothing.
__global__ __launch_bounds__(256) void gather_conv(
    const u16* __restrict__ T, const int* __restrict__ pool,
    const int* __restrict__ offs, const int* __restrict__ cnti,
    const float* __restrict__ rsin,
    int co0, int to0, int co1, int to1,
    const float* __restrict__ b1, const float* __restrict__ b2, float invn,
    u16* __restrict__ out_bf, float* __restrict__ out_f, int nDst)
{
  const int wave = threadIdx.x >> 6;
  const int lane = threadIdx.x & 63;
  const int sub  = lane >> 4;        // edge slot 0..3
  const int l15  = lane & 15;        // column group (8 cols)
  const int d = blockIdx.x * 4 + wave;
  if (d >= nDst) return;

  const int off0 = offs[co0 + d];
  const int cnt0 = cnti[co0 + d];
  const float sc0 = rsin[co0 + d];
  int off1 = 0, cnt1 = 0; float sc1 = 0.f;
  if (co1 >= 0) { off1 = offs[co1 + d]; cnt1 = cnti[co1 + d]; sc1 = rsin[co1 + d]; }
  const int tot = cnt0 + cnt1;

  float s[8];
#pragma unroll
  for (int j = 0; j < 8; ++j) s[j] = 0.f;

  for (int e = 0; e < tot; e += 8) {
    const int eA = e + sub;
    const int eB = e + 4 + sub;
    if (eA < tot) {
      bool f0 = eA < cnt0;
      int pi = f0 ? (off0 + eA) : (off1 + (eA - cnt0));
      float sc = f0 ? sc0 : sc1;
      int tb = f0 ? to0 : to1;
      int idx = pool[pi];
      short8 w = *(const short8*)(T + (((size_t)(tb + idx)) << 7) + l15 * 8);
#pragma unroll
      for (int j = 0; j < 8; ++j) s[j] += bf2f((u16)w[j]) * sc;
    }
    if (eB < tot) {
      bool f0 = eB < cnt0;
      int pi = f0 ? (off0 + eB) : (off1 + (eB - cnt0));
      float sc = f0 ? sc0 : sc1;
      int tb = f0 ? to0 : to1;
      int idx = pool[pi];
      short8 w = *(const short8*)(T + (((size_t)(tb + idx)) << 7) + l15 * 8);
#pragma unroll
      for (int j = 0; j < 8; ++j) s[j] += bf2f((u16)w[j]) * sc;
    }
  }

  // merge the 4 edge-slots
#pragma unroll
  for (int j = 0; j < 8; ++j) {
    s[j] += __shfl_xor(s[j], 16, 64);
    s[j] += __shfl_xor(s[j], 32, 64);
  }

  if (sub == 0) {
    const int col = l15 * 8;
    float v[8];
#pragma unroll
    for (int j = 0; j < 8; ++j) {
      float bb = b1[col + j] + (b2 ? b2[col + j] : 0.f);
      float x = (s[j] + bb) * invn;
      v[j] = (x > 0.f) ? x : 0.01f * x;
    }
    if (out_f) {
      float* op = out_f + (((size_t)d) << 7) + col;
      *(f32x4*)op       = (f32x4){v[0], v[1], v[2], v[3]};
      *(f32x4*)(op + 4) = (f32x4){v[4], v[5], v[6], v[7]};
    } else {
      short8 o;
#pragma unroll
      for (int j = 0; j < 8; ++j) o[j] = (short)f2bf(v[j]);
      *(short8*)(out_bf + (((size_t)d) << 7) + col) = o;
    }
  }
}

// ---------------- merged final linear over all 4 types ----------------
__global__ __launch_bounds__(256) void linear_all_k(
    const float* __restrict__ Wu, const float* __restrict__ bu,
    const float* __restrict__ Wn, const float* __restrict__ bn,
    const float* __restrict__ Wsrc, const float* __restrict__ bsrc,
    const float* __restrict__ Wf, const float* __restrict__ bfo,
    float* __restrict__ OUT)
{
  __shared__ float wsh[4][2][128];
  __shared__ float bsh[4][2];
  int tid = threadIdx.x;
  if (tid < 128) {
    wsh[0][0][tid] = Wu[tid * 2];   wsh[0][1][tid] = Wu[tid * 2 + 1];
    wsh[1][0][tid] = Wn[tid * 2];   wsh[1][1][tid] = Wn[tid * 2 + 1];
    wsh[2][0][tid] = Wsrc[tid * 2]; wsh[2][1][tid] = Wsrc[tid * 2 + 1];
    wsh[3][0][tid] = Wf[tid * 2];   wsh[3][1][tid] = Wf[tid * 2 + 1];
  } else if (tid < 132) {
    int t = tid - 128;
    const float* bp = (t == 0) ? bu : (t == 1) ? bn : (t == 2) ? bsrc : bfo;
    bsh[t][0] = bp[0]; bsh[t][1] = bp[1];
  }
  __syncthreads();
  int row = blockIdx.x * 256 + tid;
  if (row >= 505000) return;
  int t, lr; size_t hoff; int loff;
  if      (row < 200000) { t = 0; lr = row;          hoff = 1010000;  loff = 0; }
  else if (row < 300000) { t = 1; lr = row - 200000; hoff = 26610000; loff = 400000; }
  else if (row < 305000) { t = 2; lr = row - 300000; hoff = 39410000; loff = 600000; }
  else                   { t = 3; lr = row - 305000; hoff = 40050000; loff = 610000; }
  const float* hp = OUT + hoff + (size_t)lr * 128;
  float s0 = 0.f, s1 = 0.f;
#pragma unroll
  for (int k = 0; k < 128; k += 4) {
    f32x4 h4 = *(const f32x4*)(hp + k);
#pragma unroll
    for (int j = 0; j < 4; ++j) {
      s0 += h4[j] * wsh[t][0][k + j];
      s1 += h4[j] * wsh[t][1][k + j];
    }
  }
  OUT[(size_t)loff + lr * 2]     = s0 + bsh[t][0];
  OUT[(size_t)loff + lr * 2 + 1] = s1 + bsh[t][1];
}

extern "C" void kernel_launch(void* const* d_in, const int* in_sizes, int n_in,
                              void* d_out, int out_size, void* d_ws, size_t ws_size,
                              hipStream_t stream)
{
  (void)in_sizes; (void)n_in; (void)out_size; (void)ws_size;

  // ---- workspace carve-up ----
  char* wp = (char*)d_ws;
  auto take = [&](size_t bytes) { void* p = wp; wp += (bytes + 255) & ~(size_t)255; return p; };
  u16*   TP  = (u16*)take(206080000);    // per-relation GEMM-output pool (805000 rows)
  u16*   HA  = (u16*)take(129280000);    // 505000*128 bf16
  u16*   HB  = (u16*)take(129280000);
  u16*   WTA = (u16*)take(1884160);      // transposed bf16 weights arena
  float* CNT = (float*)take(3220000);    // 805000 f32 rsqrt values
  int*   CNTI = (int*)take(3220000);     // 805000 int degree counts
  int*   OFFS = (int*)take(3220000);     // 805000 int CSR offsets
  int*   CURS = (int*)take(3220000);     // 805000 int fill cursors
  int*   POOL = (int*)take(12800000);    // 3.2M int CSR src indices
  int*   BSUM = (int*)take(16384);       // scan block sums (3145)

  const int rowOff[4] = {0, 200000, 300000, 305000};   // user,news,source,follower
  const int Nt[4]     = {N_USER, N_NEWS, N_SRCT, N_FOLW};
  const int KD[4] = {128, 320, 128, 128};              // padded K per type
  const int KS[4] = {128, 300, 128, 128};
  const int WT1[4] = {0, 16384, 57344, 73728};
  const int WT2 = 90112, WTC1 = 155648, WTC2 = 548864;

  // relation table
  struct RelG { int E, srcIdx, dstIdx, srcType, dstType, srcCnt, dstCnt, tOff; };
  const RelG rels[6] = {
    {E_POSTS, 26, 27, 0, 1, 0,      200000, 0},       // posts: user->news
    {E_POSTS, 27, 26, 1, 0, 200000, 0,      200000},  // posted_by: news->user
    {E_PUB,   28, 29, 2, 1, 300000, 305000, 300000},  // publishes: source->news
    {E_PUB,   29, 28, 1, 2, 305000, 300000, 305000},  // published_by: news->source
    {E_FOLL,  30, 31, 3, 0, 405000, 605000, 405000},  // follows: follower->user
    {E_FOLL,  31, 30, 0, 3, 605000, 405000, 605000},  // followed_by: user->follower
  };

  // ---- degrees (int), merged ----
  hipMemsetAsync(CNTI, 0, NCNT * 4, stream);
  count6_k<<<12500, 256, 0, stream>>>(
      (const int*)d_in[26], (const int*)d_in[27], (const int*)d_in[28],
      (const int*)d_in[29], (const int*)d_in[30], (const int*)d_in[31], CNTI);
  rsqrt_k<<<(NCNT + 255) / 256, 256, 0, stream>>>(CNTI, CNT, NCNT);

  // ---- CSR build (once; graph static across layers) ----
  const int scanBlocks = (NCNT + 255) / 256;   // 3145
  scan1_k<<<scanBlocks, 256, 0, stream>>>(CNTI, OFFS, BSUM, NCNT);
  scan2_k<<<1, 256, 0, stream>>>(BSUM, scanBlocks);
  scan3_k<<<scanBlocks, 256, 0, stream>>>(OFFS, CNTI, BSUM, NCNT);
  hipMemsetAsync(CURS, 0, NCNT * 4, stream);
  fill6_k<<<12500, 256, 0, stream>>>(
      (const int*)d_in[26], (const int*)d_in[27],   // posts: dst=news(+200000)
      (const int*)d_in[27], (const int*)d_in[26],   // posted_by: dst=user(+0)
      (const int*)d_in[28], (const int*)d_in[29],   // publishes: dst=news(+305000)
      (const int*)d_in[29], (const int*)d_in[28],   // published_by: dst=source(+300000)
      (const int*)d_in[30], (const int*)d_in[31],   // follows: dst=user(+605000)
      (const int*)d_in[31], (const int*)d_in[30],   // followed_by: dst=follower(+405000)
      OFFS, CURS, POOL);

  // ---- weights fp32 -> bf16 k-major (merged) ----
  trans55_k<<<3520, 256, 0, stream>>>(
      (const float*)d_in[4], (const float*)d_in[8], (const float*)d_in[10],
      (const float*)d_in[12], (const float*)d_in[14], (const float*)d_in[16], WTA);
  trans_w_k<<<(40960 + 255) / 256, 256, 0, stream>>>(
      (const float*)d_in[6], WTA + WT1[1], 300, 320, 40960);

  auto gemmL = [&](const u16* A, const float* A32, int Ks, int lda, int M, int K,
                   const u16* WTp, const float* bias, const float* rs, u16* C, int leaky) {
    gemm_bf16<<<(M + 127) / 128, 256, 0, stream>>>(A, A32, Ks, lda, M, K, WTp, bias, rs, C, leaky);
  };

  // ---- stage1: h = lrelu(x @ Wi1 + bi1) -> HA  (fp32 A read + convert in-kernel) ----
  for (int t = 0; t < 4; ++t)
    gemmL(nullptr, (const float*)d_in[t], KS[t], KS[t], Nt[t], KD[t], WTA + WT1[t],
          (const float*)d_in[5 + 2 * t], nullptr, HA + (size_t)rowOff[t] * 128, 1);

  // ---- stage2: h = lrelu(h @ Wi2 + bi2) -> HB ----
  for (int t = 0; t < 4; ++t)
    gemmL(HA + (size_t)rowOff[t] * 128, nullptr, 0, 128, Nt[t], 128, WTA + WT2 + t * 16384,
          (const float*)d_in[13] + t * 128, nullptr, HB + (size_t)rowOff[t] * 128, 1);

  const size_t H1OFF[4] = {1010000, 26610000, 39410000, 40050000};
  const int relsOf[4][2] = {{1, 4}, {0, 2}, {3, -1}, {5, -1}};
  float* OUT = (float*)d_out;

  // ---- conv layers: per dst type, GEMMs then gather (T stays L2/L3-hot) ----
  for (int layer = 0; layer < 2; ++layer) {
    const u16* HIn     = layer ? HA : HB;
    const u16* wt      = WTA + (layer ? WTC2 : WTC1);
    const float* convb = (const float*)d_in[layer ? 17 : 15];
    for (int k = 0; k < 4; ++k) {
      int r1 = relsOf[k][0], r2 = relsOf[k][1];
      // T_r = (h_src * rsqrt(deg_out)) @ W[dstType][r] for this dst type's relations
      for (int j = 0; j < 2; ++j) {
        int r = relsOf[k][j];
        if (r < 0) continue;
        const RelG& q = rels[r];
        gemmL(HIn + (size_t)rowOff[q.srcType] * 128, nullptr, 0, 128, Nt[q.srcType], 128,
              wt + (size_t)(q.dstType * 6 + r) * 16384, nullptr, CNT + q.srcCnt,
              TP + (size_t)q.tOff * 128, 0);
      }
      int co0 = rels[r1].dstCnt, to0 = rels[r1].tOff;
      int co1 = (r2 >= 0) ? rels[r2].dstCnt : -1;
      int to1 = (r2 >= 0) ? rels[r2].tOff : 0;
      const float* b1 = convb + (size_t)(k * 6 + r1) * 128;
      const float* b2 = (r2 >= 0) ? convb + (size_t)(k * 6 + r2) * 128 : nullptr;
      float invn = (r2 >= 0) ? 0.5f : 1.0f;
      u16* obf  = layer ? nullptr : (HA + (size_t)rowOff[k] * 128);
      float* of = layer ? (OUT + H1OFF[k]) : nullptr;
      gather_conv<<<(Nt[k] + 3) / 4, 256, 0, stream>>>(
          TP, POOL, OFFS, CNTI, CNT, co0, to0, co1, to1, b1, b2, invn, obf, of, Nt[k]);
    }
  }

  // ---- final linear (merged): logits = h1 @ Wl + bl ----
  linear_all_k<<<(505000 + 255) / 256, 256, 0, stream>>>(
      (const float*)d_in[18], (const float*)d_in[19],
      (const float*)d_in[20], (const float*)d_in[21],
      (const float*)d_in[22], (const float*)d_in[23],
      (const float*)d_in[24], (const float*)d_in[25], OUT);
}